// Round 1
// baseline (64.628 us; speedup 1.0000x reference)
//
#include <hip/hip_runtime.h>
#include <math.h>

#define A_N   1000
#define LQ_N  2048
#define C_N   3
#define H_N   10
#define HID_N 10000   // A_N * H_N
#define MID_N 5000
#define NPOS_N 1001
#define NOUT_N 2001
#define W2COLS 6001   // MID_N + NPOS_N

__device__ __forceinline__ float sigmoidf_(float x) { return 1.0f / (1.0f + expf(-x)); }

// Kernel 1: last-timestep gather + 3 gate layers + tanh -> conc[A_N*H_N]
__global__ void __launch_bounds__(256) lstm_head(
    const float* __restrict__ quotes,
    const float* __restrict__ wih0, const float* __restrict__ bih0, const float* __restrict__ bhh0,
    const float* __restrict__ wih1, const float* __restrict__ bih1, const float* __restrict__ bhh1,
    const float* __restrict__ wih2, const float* __restrict__ bih2, const float* __restrict__ bhh2,
    float* __restrict__ conc)
{
    int a = blockIdx.x * blockDim.x + threadIdx.x;
    if (a >= A_N) return;

    const float* q = quotes + (size_t)a * LQ_N * C_N + (size_t)(LQ_N - 1) * C_N;
    float x0 = q[0], x1 = q[1], x2 = q[2];

    float g[40];
    float h[H_N];

    // layer 0: gates = x @ wih0.T + bih0 + bhh0   (wih0 is [40][3])
    #pragma unroll
    for (int j = 0; j < 40; ++j)
        g[j] = x0 * wih0[j * 3 + 0] + x1 * wih0[j * 3 + 1] + x2 * wih0[j * 3 + 2]
             + bih0[j] + bhh0[j];
    #pragma unroll
    for (int k = 0; k < H_N; ++k) {
        float cc = sigmoidf_(g[k]) * tanhf(g[20 + k]);
        h[k] = sigmoidf_(g[30 + k]) * tanhf(cc);
    }

    // layer 1  (wih1 is [40][10])
    #pragma unroll
    for (int j = 0; j < 40; ++j) {
        float s = bih1[j] + bhh1[j];
        #pragma unroll
        for (int k = 0; k < H_N; ++k) s += h[k] * wih1[j * 10 + k];
        g[j] = s;
    }
    float h2[H_N];
    #pragma unroll
    for (int k = 0; k < H_N; ++k) {
        float cc = sigmoidf_(g[k]) * tanhf(g[20 + k]);
        h2[k] = sigmoidf_(g[30 + k]) * tanhf(cc);
    }

    // layer 2  (wih2 is [40][10])
    #pragma unroll
    for (int j = 0; j < 40; ++j) {
        float s = bih2[j] + bhh2[j];
        #pragma unroll
        for (int k = 0; k < H_N; ++k) s += h2[k] * wih2[j * 10 + k];
        g[j] = s;
    }
    #pragma unroll
    for (int k = 0; k < H_N; ++k) {
        float cc = sigmoidf_(g[k]) * tanhf(g[20 + k]);
        float hh = sigmoidf_(g[30 + k]) * tanhf(cc);
        conc[a * H_N + k] = tanhf(hh);   // final tanh(h)
    }
}

// Kernel 2: lin = tanh(conc @ w1.T + b1). One wave per output row, float4 loads.
__global__ void __launch_bounds__(256) mv1(
    const float* __restrict__ w1, const float* __restrict__ b1,
    const float* __restrict__ conc, float* __restrict__ lin)
{
    int gwave = (blockIdx.x * 256 + threadIdx.x) >> 6;
    int lane  = threadIdx.x & 63;
    if (gwave >= MID_N) return;

    const float4* row = reinterpret_cast<const float4*>(w1 + (size_t)gwave * HID_N);
    const float4* v   = reinterpret_cast<const float4*>(conc);

    float acc = 0.0f;
    const int n4 = HID_N / 4;   // 2500
    for (int i = lane; i < n4; i += 64) {
        float4 a = row[i];
        float4 b = v[i];
        acc += a.x * b.x + a.y * b.y + a.z * b.z + a.w * b.w;
    }
    #pragma unroll
    for (int off = 32; off > 0; off >>= 1) acc += __shfl_down(acc, off, 64);
    if (lane == 0) lin[gwave] = tanhf(acc + b1[gwave]);
}

// Kernel 3: out = [lin, position] @ w2.T + b2. One block (256 thr) per row.
__global__ void __launch_bounds__(256) mv2(
    const float* __restrict__ w2, const float* __restrict__ b2,
    const float* __restrict__ lin, const float* __restrict__ pos,
    float* __restrict__ out)
{
    int row = blockIdx.x;
    const float* wr = w2 + (size_t)row * W2COLS;

    float acc = 0.0f;
    for (int j = threadIdx.x; j < W2COLS; j += 256) {
        float v = (j < MID_N) ? lin[j] : pos[j - MID_N];
        acc += wr[j] * v;
    }
    #pragma unroll
    for (int off = 32; off > 0; off >>= 1) acc += __shfl_down(acc, off, 64);

    __shared__ float red[4];
    int lane = threadIdx.x & 63;
    int wid  = threadIdx.x >> 6;
    if (lane == 0) red[wid] = acc;
    __syncthreads();
    if (threadIdx.x == 0)
        out[row] = red[0] + red[1] + red[2] + red[3] + b2[row];
}

extern "C" void kernel_launch(void* const* d_in, const int* in_sizes, int n_in,
                              void* d_out, int out_size, void* d_ws, size_t ws_size,
                              hipStream_t stream)
{
    const float* quotes = (const float*)d_in[0];
    const float* pos    = (const float*)d_in[1];
    const float* wih0   = (const float*)d_in[2];
    // d_in[3] = w_hh_l0 (unused by reference)
    const float* bih0   = (const float*)d_in[4];
    const float* bhh0   = (const float*)d_in[5];
    const float* wih1   = (const float*)d_in[6];
    // d_in[7] = w_hh_l1 (unused)
    const float* bih1   = (const float*)d_in[8];
    const float* bhh1   = (const float*)d_in[9];
    const float* wih2   = (const float*)d_in[10];
    // d_in[11] = w_hh_l2 (unused)
    const float* bih2   = (const float*)d_in[12];
    const float* bhh2   = (const float*)d_in[13];
    const float* w1     = (const float*)d_in[14];
    const float* b1     = (const float*)d_in[15];
    const float* w2     = (const float*)d_in[16];
    const float* b2     = (const float*)d_in[17];
    float* out = (float*)d_out;

    float* conc = (float*)d_ws;                 // HID_N floats
    float* lin  = conc + HID_N;                 // MID_N floats

    lstm_head<<<(A_N + 255) / 256, 256, 0, stream>>>(
        quotes, wih0, bih0, bhh0, wih1, bih1, bhh1, wih2, bih2, bhh2, conc);

    // 5000 rows, 4 waves per 256-thread block -> 1250 blocks
    mv1<<<MID_N / 4, 256, 0, stream>>>(w1, b1, conc, lin);

    mv2<<<NOUT_N, 256, 0, stream>>>(w2, b2, lin, pos, out);
}